// Round 9
// baseline (151.905 us; speedup 1.0000x reference)
//
#include <hip/hip_runtime.h>
#include <hip/hip_bf16.h>

// Problem constants (fixed by reference)
static constexpr int Nn  = 8192;     // nodes
static constexpr int Hh  = 4;        // heads
static constexpr int Ee  = 131072;   // edges
static constexpr int DK  = 16;       // per-head feature dim
static constexpr int CAP = 128;      // per-row bucket capacity; deg ~ Poisson(32)
static constexpr int XLEN = Hh * Nn * DK;  // 524288 floats
// Native state layout [hd][m][k] flat = hd*131072 + m*16 + k (== flat h / out;
// verified rounds 2/4/6). INTERMEDIATE buffers use permuted layout
// [v][hd*16+k] = v*64 + c so the per-entry gather is one coalesced 256B load
// (r8 win: 210 -> 146us). NOTE (r5): cg::grid_sync ~115us/sync on gfx950 —
// kernel boundaries are the cheap grid barrier. NOTE (r7): sweep iterations
// are independent loads — split-K useless; MLP comes from unrolling.
// Packed directed entry: (t<<13)|v; for equal v, packed order == t order ==
// numpy last-write-wins rank (t<E: (src,dst); t>=E: (dst,src)).

// ---------------------------------------------------------------------------
// Kernel 0: h_perm[v*64 + hd*16 + k] = h[hd*131072 + v*16 + k]; also zero cnt
// (fused here to drop the memset dispatch — scatter runs after us in-stream).
__global__ void permute_kernel(const float* __restrict__ h, float* __restrict__ h_perm,
                               int* __restrict__ cnt) {
    int j = blockIdx.x * blockDim.x + threadIdx.x;   // output index, coalesced
    if (j >= XLEN) return;
    if (j < Nn) cnt[j] = 0;
    int c = j & 63, v = j >> 6;
    int hd = c >> 4, k = c & 15;
    h_perm[j] = h[hd * (Nn * DK) + v * DK + k];
}

// ---------------------------------------------------------------------------
// Kernel 1: scatter all 2E directed entries into per-row buckets (4B packed).
__global__ void scatter_kernel(const int* __restrict__ src, const int* __restrict__ dst,
                               int* __restrict__ cnt, unsigned* __restrict__ bucket) {
    int t = blockIdx.x * blockDim.x + threadIdx.x;
    if (t >= 2 * Ee) return;
    int u, v;
    if (t < Ee) { u = src[t]; v = dst[t]; }
    else        { u = dst[t - Ee]; v = src[t - Ee]; }
    int pos = atomicAdd(&cnt[u], 1);
    if (pos < CAP) bucket[u * CAP + pos] = ((unsigned)t << 13) | (unsigned)v;
}

// ---------------------------------------------------------------------------
// Kernel 2: dedup + rowsum + normalize + SWEEP 1 fused.
// One wave per row. Survival scan is BRANCHLESS (r9: the early-break version
// diverged the wave and serialized LDS reads at latency; full-d unrolled scan
// pipelines at LDS throughput). Survivors staged in LDS; sweep 1
// (x1 = s1*(a@h)+c1*h) computed immediately from LDS coefficients.
__global__ void __launch_bounds__(256)
dedup_s1_kernel(const int* __restrict__ cnt, const unsigned* __restrict__ bucket,
                const float* __restrict__ e, const float* __restrict__ h_perm,
                int* __restrict__ cnt2, int* __restrict__ cols,
                float* __restrict__ val4, float* __restrict__ x1,
                float s1, float c1) {
    __shared__ unsigned lp[4][CAP];
    __shared__ int      lcol[4][CAP];     // prescaled v*64
    __shared__ float    lval[4][4 * CAP]; // [4*pos+hd]
    int w = threadIdx.x >> 6;
    int lane = threadIdx.x & 63;
    int u = blockIdx.x * 4 + w;
    int d = cnt[u]; if (d > CAP) d = CAP;

    for (int i = lane; i < d; i += 64)
        lp[w][i] = bucket[u * CAP + i];
    __syncthreads();

    // survival scan + per-head partial rowsums (lane owns entries lane, lane+64)
    bool  surv[2] = {false, false};
    int   vv[2];
    float ev[2][4];
    float s0 = 0.f, sA = 0.f, sB = 0.f, sC = 0.f;
#pragma unroll
    for (int r = 0; r < 2; r++) {
        int i = lane + 64 * r;
        if (i < d) {
            unsigned pi = lp[w][i];
            unsigned vi = pi & 8191u;
            bool alive = true;
            int j = 0;
            for (; j + 4 <= d; j += 4) {       // branchless, 4x unrolled
                unsigned p0 = lp[w][j],     p1 = lp[w][j + 1];
                unsigned p2 = lp[w][j + 2], p3 = lp[w][j + 3];
                alive &= !(((p0 & 8191u) == vi) & (p0 > pi));
                alive &= !(((p1 & 8191u) == vi) & (p1 > pi));
                alive &= !(((p2 & 8191u) == vi) & (p2 > pi));
                alive &= !(((p3 & 8191u) == vi) & (p3 > pi));
            }
            for (; j < d; j++) {
                unsigned pj = lp[w][j];
                alive &= !(((pj & 8191u) == vi) & (pj > pi));
            }
            surv[r] = alive;
            vv[r] = (int)vi;
            if (alive) {
                int t = (int)(pi >> 13);
                int edge = (t >= Ee) ? (t - Ee) : t;
                ev[r][0] = e[0 * Ee + edge];
                ev[r][1] = e[1 * Ee + edge];
                ev[r][2] = e[2 * Ee + edge];
                ev[r][3] = e[3 * Ee + edge];
                s0 += ev[r][0]; sA += ev[r][1]; sB += ev[r][2]; sC += ev[r][3];
            }
        }
    }
#pragma unroll
    for (int off = 32; off > 0; off >>= 1) {
        s0 += __shfl_xor(s0, off, 64);
        sA += __shfl_xor(sA, off, 64);
        sB += __shfl_xor(sB, off, 64);
        sC += __shfl_xor(sC, off, 64);
    }
    float i0 = 1.f / s0, i1 = 1.f / sA, i2 = 1.f / sB, i3 = 1.f / sC;

    // ballot-compact survivors
    unsigned long long m0 = __ballot(surv[0]);
    unsigned long long m1 = __ballot(surv[1]);
    unsigned long long below = ((unsigned long long)1 << lane) - 1;
    int base1 = __popcll(m0);
    int pos[2];
    pos[0] = __popcll(m0 & below);
    pos[1] = base1 + __popcll(m1 & below);
    int total = base1 + __popcll(m1);
#pragma unroll
    for (int r = 0; r < 2; r++) {
        if (surv[r]) {
            float f0 = ev[r][0] * i0, f1 = ev[r][1] * i1,
                  f2 = ev[r][2] * i2, f3 = ev[r][3] * i3;
            int q = u * CAP + pos[r];
            int vcol = vv[r] << 6;            // prescaled for perm layout
            cols[q] = vcol;
            val4[4 * q + 0] = f0; val4[4 * q + 1] = f1;
            val4[4 * q + 2] = f2; val4[4 * q + 3] = f3;
            lcol[w][pos[r]] = vcol;
            lval[w][4 * pos[r] + 0] = f0; lval[w][4 * pos[r] + 1] = f1;
            lval[w][4 * pos[r] + 2] = f2; lval[w][4 * pos[r] + 3] = f3;
        }
    }
    if (lane == 0) cnt2[u] = total;

    // ---- sweep 1 from LDS (wave-local; no barrier needed for own ds ops) ----
    int hd = lane >> 4;
    float a0 = 0.f, a1 = 0.f;
    int p = 0;
    for (; p + 2 <= total; p += 2) {
        a0 += lval[w][4 * p + hd] * h_perm[lcol[w][p] + lane];
        a1 += lval[w][4 * (p + 1) + hd] * h_perm[lcol[w][p + 1] + lane];
    }
    if (p < total) a0 += lval[w][4 * p + hd] * h_perm[lcol[w][p] + lane];
    int oi = (u << 6) + lane;
    x1[oi] = s1 * (a0 + a1) + c1 * h_perm[oi];
}

// ---------------------------------------------------------------------------
// Kernel 3: one Horner sweep in permuted layout.  xn = s_k*(a@x) + c_k*h_perm
// One wave per row; ONE coalesced 256B gather per entry; 8x unroll for MLP
// (r9: 8 outstanding gathers halve the dependent L2-latency batches).
__global__ void __launch_bounds__(256)
spmv_kernel(const int* __restrict__ cnt2, const int* __restrict__ cols,
            const float* __restrict__ val4, const float* __restrict__ x,
            const float* __restrict__ h_perm, float* __restrict__ xn,
            float s_k, float c_k) {
    int u = blockIdx.x * (blockDim.x >> 6) + (threadIdx.x >> 6);
    int lane = threadIdx.x & 63;
    int hd = lane >> 4;
    int d = cnt2[u];
    int base = u * CAP;
    float a0 = 0.f, a1 = 0.f, a2 = 0.f, a3 = 0.f;
    float a4 = 0.f, a5 = 0.f, a6 = 0.f, a7 = 0.f;
    int p = 0;
    for (; p + 8 <= d; p += 8) {
        int q = base + p;
        int c0 = cols[q],     c1_ = cols[q + 1], c2 = cols[q + 2], c3 = cols[q + 3];
        int c4 = cols[q + 4], c5 = cols[q + 5],  c6 = cols[q + 6], c7 = cols[q + 7];
        float f0 = val4[4 * q + hd];
        float f1 = val4[4 * (q + 1) + hd];
        float f2 = val4[4 * (q + 2) + hd];
        float f3 = val4[4 * (q + 3) + hd];
        float f4 = val4[4 * (q + 4) + hd];
        float f5 = val4[4 * (q + 5) + hd];
        float f6 = val4[4 * (q + 6) + hd];
        float f7 = val4[4 * (q + 7) + hd];
        a0 += f0 * x[c0 + lane];
        a1 += f1 * x[c1_ + lane];
        a2 += f2 * x[c2 + lane];
        a3 += f3 * x[c3 + lane];
        a4 += f4 * x[c4 + lane];
        a5 += f5 * x[c5 + lane];
        a6 += f6 * x[c6 + lane];
        a7 += f7 * x[c7 + lane];
    }
    for (; p < d; p++) {
        int q = base + p;
        a0 += val4[4 * q + hd] * x[cols[q] + lane];
    }
    int oi = (u << 6) + lane;
    float acc = ((a0 + a1) + (a2 + a3)) + ((a4 + a5) + (a6 + a7));
    xn[oi] = s_k * acc + c_k * h_perm[oi];
}

// ---------------------------------------------------------------------------
// Kernel 4: final sweep — same but writes NATIVE layout d_out.
__global__ void __launch_bounds__(256)
spmv_last_kernel(const int* __restrict__ cnt2, const int* __restrict__ cols,
                 const float* __restrict__ val4, const float* __restrict__ x,
                 const float* __restrict__ h_perm, float* __restrict__ out,
                 float s_k, float c_k) {
    int u = blockIdx.x * (blockDim.x >> 6) + (threadIdx.x >> 6);
    int lane = threadIdx.x & 63;
    int hd = lane >> 4, k = lane & 15;
    int d = cnt2[u];
    int base = u * CAP;
    float a0 = 0.f, a1 = 0.f, a2 = 0.f, a3 = 0.f;
    float a4 = 0.f, a5 = 0.f, a6 = 0.f, a7 = 0.f;
    int p = 0;
    for (; p + 8 <= d; p += 8) {
        int q = base + p;
        int c0 = cols[q],     c1_ = cols[q + 1], c2 = cols[q + 2], c3 = cols[q + 3];
        int c4 = cols[q + 4], c5 = cols[q + 5],  c6 = cols[q + 6], c7 = cols[q + 7];
        float f0 = val4[4 * q + hd];
        float f1 = val4[4 * (q + 1) + hd];
        float f2 = val4[4 * (q + 2) + hd];
        float f3 = val4[4 * (q + 3) + hd];
        float f4 = val4[4 * (q + 4) + hd];
        float f5 = val4[4 * (q + 5) + hd];
        float f6 = val4[4 * (q + 6) + hd];
        float f7 = val4[4 * (q + 7) + hd];
        a0 += f0 * x[c0 + lane];
        a1 += f1 * x[c1_ + lane];
        a2 += f2 * x[c2 + lane];
        a3 += f3 * x[c3 + lane];
        a4 += f4 * x[c4 + lane];
        a5 += f5 * x[c5 + lane];
        a6 += f6 * x[c6 + lane];
        a7 += f7 * x[c7 + lane];
    }
    for (; p < d; p++) {
        int q = base + p;
        a0 += val4[4 * q + hd] * x[cols[q] + lane];
    }
    float acc = ((a0 + a1) + (a2 + a3)) + ((a4 + a5) + (a6 + a7));
    float r = s_k * acc + c_k * h_perm[(u << 6) + lane];
    out[hd * (Nn * DK) + u * DK + k] = r;   // native layout
}

// ---------------------------------------------------------------------------
extern "C" void kernel_launch(void* const* d_in, const int* in_sizes, int n_in,
                              void* d_out, int out_size, void* d_ws, size_t ws_size,
                              hipStream_t stream) {
    const float* h = (const float*)d_in[0];
    const float* e = (const float*)d_in[1];
    const int* src = (const int*)d_in[2];
    const int* dst = (const int*)d_in[3];
    float* out = (float*)d_out;

    // Workspace carve-up (~31 MB)
    char* ws = (char*)d_ws;
    size_t off = 0;
    auto alloc = [&](size_t bytes) -> void* {
        void* p = ws + off;
        off = (off + bytes + 255) & ~(size_t)255;
        return p;
    };
    int*      cnt    = (int*)     alloc((size_t)Nn * 4);
    int*      cnt2   = (int*)     alloc((size_t)Nn * 4);
    unsigned* bucket = (unsigned*)alloc((size_t)Nn * CAP * 4);      // 4 MB
    int*      cols   = (int*)     alloc((size_t)Nn * CAP * 4);      // 4 MB
    float*    val4   = (float*)   alloc((size_t)Nn * CAP * 4 * 4);  // 16 MB
    float*    h_perm = (float*)   alloc((size_t)XLEN * 4);          // 2 MB
    float*    bufA   = (float*)   alloc((size_t)XLEN * 4);          // 2 MB
    float*    bufB   = (float*)   alloc((size_t)XLEN * 4);          // 2 MB

    const int tpb = 256;

    permute_kernel<<<XLEN / tpb, tpb, 0, stream>>>(h, h_perm, cnt);
    scatter_kernel<<<(2 * Ee) / tpb, tpb, 0, stream>>>(src, dst, cnt, bucket);

    // Horner: r1 = (1/720) a h + (1/120) h; r_{k+1} = a r_k + c_k h; out = r6
    const float s_k[6] = {1.f / 720.f, 1.f, 1.f, 1.f, 1.f, 1.f};
    const float c_k[6] = {1.f / 120.f, 1.f / 24.f, 1.f / 6.f, 0.5f, 1.f, 1.f};

    dedup_s1_kernel<<<Nn / 4, tpb, 0, stream>>>(cnt, bucket, e, h_perm, cnt2,
                                                cols, val4, bufA, s_k[0], c_k[0]);
    spmv_kernel<<<Nn / 4, tpb, 0, stream>>>(cnt2, cols, val4, bufA, h_perm, bufB, s_k[1], c_k[1]);
    spmv_kernel<<<Nn / 4, tpb, 0, stream>>>(cnt2, cols, val4, bufB, h_perm, bufA, s_k[2], c_k[2]);
    spmv_kernel<<<Nn / 4, tpb, 0, stream>>>(cnt2, cols, val4, bufA, h_perm, bufB, s_k[3], c_k[3]);
    spmv_kernel<<<Nn / 4, tpb, 0, stream>>>(cnt2, cols, val4, bufB, h_perm, bufA, s_k[4], c_k[4]);
    spmv_last_kernel<<<Nn / 4, tpb, 0, stream>>>(cnt2, cols, val4, bufA, h_perm, out, s_k[5], c_k[5]);
}

// Round 10
// 141.141 us; speedup vs baseline: 1.0763x; 1.0763x over previous
//
#include <hip/hip_runtime.h>
#include <hip/hip_bf16.h>

// Problem constants (fixed by reference)
static constexpr int Nn  = 8192;     // nodes
static constexpr int Hh  = 4;        // heads
static constexpr int Ee  = 131072;   // edges
static constexpr int DK  = 16;       // per-head feature dim
static constexpr int CAP = 128;      // per-row bucket capacity; deg ~ Poisson(32)
static constexpr int XLEN = Hh * Nn * DK;  // 524288 elements
// Native state layout [hd][m][k] flat = hd*131072 + m*16 + k (== flat h / out;
// verified rounds 2/4/6). INTERMEDIATE buffers use permuted layout
// [v][hd*16+k] = v*64 + c; r8 win (210->146us) came from this making the
// per-entry gather one coalesced load. r10: intermediates in BF16 -> gather is
// ONE 128B L2 line per entry (was 2); h_perm/val4 stay fp32 for precision.
// NOTE (r5): cg::grid_sync ~115us/sync on gfx950 — kernel boundaries are the
// cheap grid barrier. NOTE (r7/r9): sweep loads are independent; 4x unroll is
// enough MLP at 32 waves/CU — split-K and 8x unroll were neutral.
// Packed directed entry: (t<<13)|v; for equal v, packed order == t order ==
// numpy last-write-wins rank (t<E: (src,dst); t>=E: (dst,src)).

// ---------------------------------------------------------------------------
// Kernel 0: h_perm[v*64 + hd*16 + k] = h[hd*131072 + v*16 + k]; also zero cnt
// (fused to drop the memset dispatch — scatter runs after us in-stream).
__global__ void permute_kernel(const float* __restrict__ h, float* __restrict__ h_perm,
                               int* __restrict__ cnt) {
    int j = blockIdx.x * blockDim.x + threadIdx.x;   // output index, coalesced
    if (j >= XLEN) return;
    if (j < Nn) cnt[j] = 0;
    int c = j & 63, v = j >> 6;
    int hd = c >> 4, k = c & 15;
    h_perm[j] = h[hd * (Nn * DK) + v * DK + k];
}

// ---------------------------------------------------------------------------
// Kernel 1: scatter all 2E directed entries into per-row buckets (4B packed).
__global__ void scatter_kernel(const int* __restrict__ src, const int* __restrict__ dst,
                               int* __restrict__ cnt, unsigned* __restrict__ bucket) {
    int t = blockIdx.x * blockDim.x + threadIdx.x;
    if (t >= 2 * Ee) return;
    int u, v;
    if (t < Ee) { u = src[t]; v = dst[t]; }
    else        { u = dst[t - Ee]; v = src[t - Ee]; }
    int pos = atomicAdd(&cnt[u], 1);
    if (pos < CAP) bucket[u * CAP + pos] = ((unsigned)t << 13) | (unsigned)v;
}

// ---------------------------------------------------------------------------
// Kernel 2: dedup + rowsum + normalize + SWEEP 1 fused.
// One wave per row. Early-break survival scan (duplicates are rare — the
// branch almost never fires, no divergence cost; r9's branchless was neutral).
// Survivors staged in LDS; sweep 1 (x1 = s1*(a@h)+c1*h) computed immediately.
__global__ void __launch_bounds__(256)
dedup_s1_kernel(const int* __restrict__ cnt, const unsigned* __restrict__ bucket,
                const float* __restrict__ e, const float* __restrict__ h_perm,
                int* __restrict__ cnt2, int* __restrict__ cols,
                float* __restrict__ val4, __hip_bfloat16* __restrict__ x1,
                float s1, float c1) {
    __shared__ unsigned lp[4][CAP];
    __shared__ int      lcol[4][CAP];     // prescaled v*64
    __shared__ float    lval[4][4 * CAP]; // [4*pos+hd]
    int w = threadIdx.x >> 6;
    int lane = threadIdx.x & 63;
    int u = blockIdx.x * 4 + w;
    int d = cnt[u]; if (d > CAP) d = CAP;

    for (int i = lane; i < d; i += 64)
        lp[w][i] = bucket[u * CAP + i];
    __syncthreads();

    // survival scan + per-head partial rowsums (lane owns entries lane, lane+64)
    bool  surv[2] = {false, false};
    int   vv[2];
    float ev[2][4];
    float s0 = 0.f, sA = 0.f, sB = 0.f, sC = 0.f;
#pragma unroll
    for (int r = 0; r < 2; r++) {
        int i = lane + 64 * r;
        if (i < d) {
            unsigned pi = lp[w][i];
            unsigned vi = pi & 8191u;
            bool alive = true;
            for (int j = 0; j < d; j++) {
                unsigned pj = lp[w][j];
                if ((pj & 8191u) == vi && pj > pi) { alive = false; break; }
            }
            surv[r] = alive;
            vv[r] = (int)vi;
            if (alive) {
                int t = (int)(pi >> 13);
                int edge = (t >= Ee) ? (t - Ee) : t;
                ev[r][0] = e[0 * Ee + edge];
                ev[r][1] = e[1 * Ee + edge];
                ev[r][2] = e[2 * Ee + edge];
                ev[r][3] = e[3 * Ee + edge];
                s0 += ev[r][0]; sA += ev[r][1]; sB += ev[r][2]; sC += ev[r][3];
            }
        }
    }
#pragma unroll
    for (int off = 32; off > 0; off >>= 1) {
        s0 += __shfl_xor(s0, off, 64);
        sA += __shfl_xor(sA, off, 64);
        sB += __shfl_xor(sB, off, 64);
        sC += __shfl_xor(sC, off, 64);
    }
    float i0 = 1.f / s0, i1 = 1.f / sA, i2 = 1.f / sB, i3 = 1.f / sC;

    // ballot-compact survivors
    unsigned long long m0 = __ballot(surv[0]);
    unsigned long long m1 = __ballot(surv[1]);
    unsigned long long below = ((unsigned long long)1 << lane) - 1;
    int base1 = __popcll(m0);
    int pos[2];
    pos[0] = __popcll(m0 & below);
    pos[1] = base1 + __popcll(m1 & below);
    int total = base1 + __popcll(m1);
#pragma unroll
    for (int r = 0; r < 2; r++) {
        if (surv[r]) {
            float f0 = ev[r][0] * i0, f1 = ev[r][1] * i1,
                  f2 = ev[r][2] * i2, f3 = ev[r][3] * i3;
            int q = u * CAP + pos[r];
            int vcol = vv[r] << 6;            // prescaled for perm layout
            cols[q] = vcol;
            val4[4 * q + 0] = f0; val4[4 * q + 1] = f1;
            val4[4 * q + 2] = f2; val4[4 * q + 3] = f3;
            lcol[w][pos[r]] = vcol;
            lval[w][4 * pos[r] + 0] = f0; lval[w][4 * pos[r] + 1] = f1;
            lval[w][4 * pos[r] + 2] = f2; lval[w][4 * pos[r] + 3] = f3;
        }
    }
    if (lane == 0) cnt2[u] = total;

    // ---- sweep 1 from LDS (wave-local; no barrier needed for own ds ops) ----
    int hd = lane >> 4;
    float a0 = 0.f, a1 = 0.f;
    int p = 0;
    for (; p + 2 <= total; p += 2) {
        a0 += lval[w][4 * p + hd] * h_perm[lcol[w][p] + lane];
        a1 += lval[w][4 * (p + 1) + hd] * h_perm[lcol[w][p + 1] + lane];
    }
    if (p < total) a0 += lval[w][4 * p + hd] * h_perm[lcol[w][p] + lane];
    int oi = (u << 6) + lane;
    x1[oi] = __float2bfloat16(s1 * (a0 + a1) + c1 * h_perm[oi]);
}

// ---------------------------------------------------------------------------
// Kernel 3: one Horner sweep in permuted layout.  xn = s_k*(a@x) + c_k*h_perm
// One wave per row; per entry ONE coalesced 128B bf16 gather; 4x unroll;
// fp32 accumulation; bf16 store of the intermediate.
__global__ void __launch_bounds__(256)
spmv_kernel(const int* __restrict__ cnt2, const int* __restrict__ cols,
            const float* __restrict__ val4, const __hip_bfloat16* __restrict__ x,
            const float* __restrict__ h_perm, __hip_bfloat16* __restrict__ xn,
            float s_k, float c_k) {
    int u = blockIdx.x * (blockDim.x >> 6) + (threadIdx.x >> 6);
    int lane = threadIdx.x & 63;
    int hd = lane >> 4;
    int d = cnt2[u];
    int base = u * CAP;
    float a0 = 0.f, a1 = 0.f, a2 = 0.f, a3 = 0.f;
    int p = 0;
    for (; p + 4 <= d; p += 4) {
        int q = base + p;
        int c0 = cols[q], c1_ = cols[q + 1], c2 = cols[q + 2], c3 = cols[q + 3];
        float f0 = val4[4 * q + hd];
        float f1 = val4[4 * (q + 1) + hd];
        float f2 = val4[4 * (q + 2) + hd];
        float f3 = val4[4 * (q + 3) + hd];
        a0 += f0 * __bfloat162float(x[c0 + lane]);
        a1 += f1 * __bfloat162float(x[c1_ + lane]);
        a2 += f2 * __bfloat162float(x[c2 + lane]);
        a3 += f3 * __bfloat162float(x[c3 + lane]);
    }
    for (; p < d; p++) {
        int q = base + p;
        a0 += val4[4 * q + hd] * __bfloat162float(x[cols[q] + lane]);
    }
    int oi = (u << 6) + lane;
    float acc = (a0 + a1) + (a2 + a3);
    xn[oi] = __float2bfloat16(s_k * acc + c_k * h_perm[oi]);
}

// ---------------------------------------------------------------------------
// Kernel 4: final sweep — bf16 gather, fp32 result in NATIVE layout d_out.
__global__ void __launch_bounds__(256)
spmv_last_kernel(const int* __restrict__ cnt2, const int* __restrict__ cols,
                 const float* __restrict__ val4, const __hip_bfloat16* __restrict__ x,
                 const float* __restrict__ h_perm, float* __restrict__ out,
                 float s_k, float c_k) {
    int u = blockIdx.x * (blockDim.x >> 6) + (threadIdx.x >> 6);
    int lane = threadIdx.x & 63;
    int hd = lane >> 4, k = lane & 15;
    int d = cnt2[u];
    int base = u * CAP;
    float a0 = 0.f, a1 = 0.f, a2 = 0.f, a3 = 0.f;
    int p = 0;
    for (; p + 4 <= d; p += 4) {
        int q = base + p;
        int c0 = cols[q], c1_ = cols[q + 1], c2 = cols[q + 2], c3 = cols[q + 3];
        float f0 = val4[4 * q + hd];
        float f1 = val4[4 * (q + 1) + hd];
        float f2 = val4[4 * (q + 2) + hd];
        float f3 = val4[4 * (q + 3) + hd];
        a0 += f0 * __bfloat162float(x[c0 + lane]);
        a1 += f1 * __bfloat162float(x[c1_ + lane]);
        a2 += f2 * __bfloat162float(x[c2 + lane]);
        a3 += f3 * __bfloat162float(x[c3 + lane]);
    }
    for (; p < d; p++) {
        int q = base + p;
        a0 += val4[4 * q + hd] * __bfloat162float(x[cols[q] + lane]);
    }
    float acc = (a0 + a1) + (a2 + a3);
    float r = s_k * acc + c_k * h_perm[(u << 6) + lane];
    out[hd * (Nn * DK) + u * DK + k] = r;   // native layout
}

// ---------------------------------------------------------------------------
extern "C" void kernel_launch(void* const* d_in, const int* in_sizes, int n_in,
                              void* d_out, int out_size, void* d_ws, size_t ws_size,
                              hipStream_t stream) {
    const float* h = (const float*)d_in[0];
    const float* e = (const float*)d_in[1];
    const int* src = (const int*)d_in[2];
    const int* dst = (const int*)d_in[3];
    float* out = (float*)d_out;

    // Workspace carve-up (~28 MB)
    char* ws = (char*)d_ws;
    size_t off = 0;
    auto alloc = [&](size_t bytes) -> void* {
        void* p = ws + off;
        off = (off + bytes + 255) & ~(size_t)255;
        return p;
    };
    int*            cnt    = (int*)            alloc((size_t)Nn * 4);
    int*            cnt2   = (int*)            alloc((size_t)Nn * 4);
    unsigned*       bucket = (unsigned*)       alloc((size_t)Nn * CAP * 4);      // 4 MB
    int*            cols   = (int*)            alloc((size_t)Nn * CAP * 4);      // 4 MB
    float*          val4   = (float*)          alloc((size_t)Nn * CAP * 4 * 4);  // 16 MB
    float*          h_perm = (float*)          alloc((size_t)XLEN * 4);          // 2 MB
    __hip_bfloat16* bufA   = (__hip_bfloat16*) alloc((size_t)XLEN * 2);          // 1 MB
    __hip_bfloat16* bufB   = (__hip_bfloat16*) alloc((size_t)XLEN * 2);          // 1 MB

    const int tpb = 256;

    permute_kernel<<<XLEN / tpb, tpb, 0, stream>>>(h, h_perm, cnt);
    scatter_kernel<<<(2 * Ee) / tpb, tpb, 0, stream>>>(src, dst, cnt, bucket);

    // Horner: r1 = (1/720) a h + (1/120) h; r_{k+1} = a r_k + c_k h; out = r6
    const float s_k[6] = {1.f / 720.f, 1.f, 1.f, 1.f, 1.f, 1.f};
    const float c_k[6] = {1.f / 120.f, 1.f / 24.f, 1.f / 6.f, 0.5f, 1.f, 1.f};

    dedup_s1_kernel<<<Nn / 4, tpb, 0, stream>>>(cnt, bucket, e, h_perm, cnt2,
                                                cols, val4, bufA, s_k[0], c_k[0]);
    spmv_kernel<<<Nn / 4, tpb, 0, stream>>>(cnt2, cols, val4, bufA, h_perm, bufB, s_k[1], c_k[1]);
    spmv_kernel<<<Nn / 4, tpb, 0, stream>>>(cnt2, cols, val4, bufB, h_perm, bufA, s_k[2], c_k[2]);
    spmv_kernel<<<Nn / 4, tpb, 0, stream>>>(cnt2, cols, val4, bufA, h_perm, bufB, s_k[3], c_k[3]);
    spmv_kernel<<<Nn / 4, tpb, 0, stream>>>(cnt2, cols, val4, bufB, h_perm, bufA, s_k[4], c_k[4]);
    spmv_last_kernel<<<Nn / 4, tpb, 0, stream>>>(cnt2, cols, val4, bufA, h_perm, out, s_k[5], c_k[5]);
}

// Round 11
// 141.059 us; speedup vs baseline: 1.0769x; 1.0006x over previous
//
#include <hip/hip_runtime.h>
#include <hip/hip_bf16.h>

// Problem constants (fixed by reference)
static constexpr int Nn  = 8192;     // nodes
static constexpr int Hh  = 4;        // heads
static constexpr int Ee  = 131072;   // edges
static constexpr int DK  = 16;       // per-head feature dim
static constexpr int CAP = 128;      // per-row bucket capacity; deg ~ Poisson(32)
static constexpr int XLEN = Hh * Nn * DK;  // 524288 elements
// Native state layout [hd][m][k] flat = hd*131072 + m*16 + k (== flat h / out;
// verified rounds 2/4/6). INTERMEDIATE buffers use permuted layout
// [v][hd*16+k] = v*64 + c; r8 win (210->146us): per-entry gather is one
// coalesced load. r10 win (146->141): intermediates in BF16 -> one 128B line
// per gather; h_perm/val4 stay fp32. r11: e transposed once to e4[edge]
// (float4) so dedup does ONE 16B load per entry instead of 4 scattered 4B.
// NOTE (r5): cg::grid_sync ~115us/sync on gfx950 — kernel boundaries are the
// cheap grid barrier. NOTE (r7/r9): sweep loads are independent; 4x unroll is
// enough MLP at 32 waves/CU — split-K and 8x unroll were neutral.
// Packed directed entry: (t<<13)|v; for equal v, packed order == t order ==
// numpy last-write-wins rank (t<E: (src,dst); t>=E: (dst,src)).

// ---------------------------------------------------------------------------
// Kernel 0: h_perm[v*64+hd*16+k] = h[hd*131072+v*16+k]; zero cnt (drops the
// memset dispatch); transpose e into e4[edge] = {e0,e1,e2,e3} (4 coalesced
// input streams -> one 16B-aligned float4 per edge).
__global__ void permute_kernel(const float* __restrict__ h, float* __restrict__ h_perm,
                               const float* __restrict__ e, float4* __restrict__ e4,
                               int* __restrict__ cnt) {
    int j = blockIdx.x * blockDim.x + threadIdx.x;   // output index, coalesced
    if (j >= XLEN) return;
    if (j < Nn) cnt[j] = 0;
    if (j < Ee)
        e4[j] = make_float4(e[j], e[Ee + j], e[2 * Ee + j], e[3 * Ee + j]);
    int c = j & 63, v = j >> 6;
    int hd = c >> 4, k = c & 15;
    h_perm[j] = h[hd * (Nn * DK) + v * DK + k];
}

// ---------------------------------------------------------------------------
// Kernel 1: scatter all 2E directed entries into per-row buckets (4B packed).
__global__ void scatter_kernel(const int* __restrict__ src, const int* __restrict__ dst,
                               int* __restrict__ cnt, unsigned* __restrict__ bucket) {
    int t = blockIdx.x * blockDim.x + threadIdx.x;
    if (t >= 2 * Ee) return;
    int u, v;
    if (t < Ee) { u = src[t]; v = dst[t]; }
    else        { u = dst[t - Ee]; v = src[t - Ee]; }
    int pos = atomicAdd(&cnt[u], 1);
    if (pos < CAP) bucket[u * CAP + pos] = ((unsigned)t << 13) | (unsigned)v;
}

// ---------------------------------------------------------------------------
// Kernel 2: dedup + rowsum + normalize + SWEEP 1 fused.
// One wave per row. e4 load issued BEFORE the survival scan so its L2 latency
// hides behind the LDS scan. Early-break scan (duplicates are rare; r9's
// branchless version was neutral). Survivors staged in LDS; sweep 1
// (x1 = s1*(a@h)+c1*h) computed immediately from LDS coefficients.
__global__ void __launch_bounds__(256)
dedup_s1_kernel(const int* __restrict__ cnt, const unsigned* __restrict__ bucket,
                const float4* __restrict__ e4, const float* __restrict__ h_perm,
                int* __restrict__ cnt2, int* __restrict__ cols,
                float* __restrict__ val4, __hip_bfloat16* __restrict__ x1,
                float s1, float c1) {
    __shared__ unsigned lp[4][CAP];
    __shared__ int      lcol[4][CAP];     // prescaled v*64
    __shared__ float    lval[4][4 * CAP]; // [4*pos+hd]
    int w = threadIdx.x >> 6;
    int lane = threadIdx.x & 63;
    int u = blockIdx.x * 4 + w;
    int d = cnt[u]; if (d > CAP) d = CAP;

    for (int i = lane; i < d; i += 64)
        lp[w][i] = bucket[u * CAP + i];
    __syncthreads();

    // survival scan + per-head partial rowsums (lane owns entries lane, lane+64)
    bool  surv[2] = {false, false};
    int   vv[2];
    float4 q4[2];
    float s0 = 0.f, sA = 0.f, sB = 0.f, sC = 0.f;
#pragma unroll
    for (int r = 0; r < 2; r++) {
        int i = lane + 64 * r;
        bool valid = (i < d);
        unsigned pi = valid ? lp[w][i] : 0u;
        unsigned vi = pi & 8191u;
        int t = (int)(pi >> 13);
        int edge = (t >= Ee) ? (t - Ee) : t;
        q4[r] = e4[edge];                  // issued early; latency hides in scan
        bool alive = valid;
        if (valid) {
            for (int j = 0; j < d; j++) {
                unsigned pj = lp[w][j];
                if ((pj & 8191u) == vi && pj > pi) { alive = false; break; }
            }
        }
        surv[r] = alive;
        vv[r] = (int)vi;
        if (alive) {
            s0 += q4[r].x; sA += q4[r].y; sB += q4[r].z; sC += q4[r].w;
        }
    }
#pragma unroll
    for (int off = 32; off > 0; off >>= 1) {
        s0 += __shfl_xor(s0, off, 64);
        sA += __shfl_xor(sA, off, 64);
        sB += __shfl_xor(sB, off, 64);
        sC += __shfl_xor(sC, off, 64);
    }
    float i0 = 1.f / s0, i1 = 1.f / sA, i2 = 1.f / sB, i3 = 1.f / sC;

    // ballot-compact survivors
    unsigned long long m0 = __ballot(surv[0]);
    unsigned long long m1 = __ballot(surv[1]);
    unsigned long long below = ((unsigned long long)1 << lane) - 1;
    int base1 = __popcll(m0);
    int pos[2];
    pos[0] = __popcll(m0 & below);
    pos[1] = base1 + __popcll(m1 & below);
    int total = base1 + __popcll(m1);
#pragma unroll
    for (int r = 0; r < 2; r++) {
        if (surv[r]) {
            float f0 = q4[r].x * i0, f1 = q4[r].y * i1,
                  f2 = q4[r].z * i2, f3 = q4[r].w * i3;
            int q = u * CAP + pos[r];
            int vcol = vv[r] << 6;            // prescaled for perm layout
            cols[q] = vcol;
            val4[4 * q + 0] = f0; val4[4 * q + 1] = f1;
            val4[4 * q + 2] = f2; val4[4 * q + 3] = f3;
            lcol[w][pos[r]] = vcol;
            lval[w][4 * pos[r] + 0] = f0; lval[w][4 * pos[r] + 1] = f1;
            lval[w][4 * pos[r] + 2] = f2; lval[w][4 * pos[r] + 3] = f3;
        }
    }
    if (lane == 0) cnt2[u] = total;

    // ---- sweep 1 from LDS (wave-local; no barrier needed for own ds ops) ----
    int hd = lane >> 4;
    float a0 = 0.f, a1 = 0.f;
    int p = 0;
    for (; p + 2 <= total; p += 2) {
        a0 += lval[w][4 * p + hd] * h_perm[lcol[w][p] + lane];
        a1 += lval[w][4 * (p + 1) + hd] * h_perm[lcol[w][p + 1] + lane];
    }
    if (p < total) a0 += lval[w][4 * p + hd] * h_perm[lcol[w][p] + lane];
    int oi = (u << 6) + lane;
    x1[oi] = __float2bfloat16(s1 * (a0 + a1) + c1 * h_perm[oi]);
}

// ---------------------------------------------------------------------------
// Kernel 3: one Horner sweep in permuted layout.  xn = s_k*(a@x) + c_k*h_perm
// One wave per row; per entry ONE coalesced 128B bf16 gather; 4x unroll;
// fp32 accumulation; bf16 store of the intermediate.
__global__ void __launch_bounds__(256)
spmv_kernel(const int* __restrict__ cnt2, const int* __restrict__ cols,
            const float* __restrict__ val4, const __hip_bfloat16* __restrict__ x,
            const float* __restrict__ h_perm, __hip_bfloat16* __restrict__ xn,
            float s_k, float c_k) {
    int u = blockIdx.x * (blockDim.x >> 6) + (threadIdx.x >> 6);
    int lane = threadIdx.x & 63;
    int hd = lane >> 4;
    int d = cnt2[u];
    int base = u * CAP;
    float a0 = 0.f, a1 = 0.f, a2 = 0.f, a3 = 0.f;
    int p = 0;
    for (; p + 4 <= d; p += 4) {
        int q = base + p;
        int c0 = cols[q], c1_ = cols[q + 1], c2 = cols[q + 2], c3 = cols[q + 3];
        float f0 = val4[4 * q + hd];
        float f1 = val4[4 * (q + 1) + hd];
        float f2 = val4[4 * (q + 2) + hd];
        float f3 = val4[4 * (q + 3) + hd];
        a0 += f0 * __bfloat162float(x[c0 + lane]);
        a1 += f1 * __bfloat162float(x[c1_ + lane]);
        a2 += f2 * __bfloat162float(x[c2 + lane]);
        a3 += f3 * __bfloat162float(x[c3 + lane]);
    }
    for (; p < d; p++) {
        int q = base + p;
        a0 += val4[4 * q + hd] * __bfloat162float(x[cols[q] + lane]);
    }
    int oi = (u << 6) + lane;
    float acc = (a0 + a1) + (a2 + a3);
    xn[oi] = __float2bfloat16(s_k * acc + c_k * h_perm[oi]);
}

// ---------------------------------------------------------------------------
// Kernel 4: final sweep — bf16 gather, fp32 result in NATIVE layout d_out.
__global__ void __launch_bounds__(256)
spmv_last_kernel(const int* __restrict__ cnt2, const int* __restrict__ cols,
                 const float* __restrict__ val4, const __hip_bfloat16* __restrict__ x,
                 const float* __restrict__ h_perm, float* __restrict__ out,
                 float s_k, float c_k) {
    int u = blockIdx.x * (blockDim.x >> 6) + (threadIdx.x >> 6);
    int lane = threadIdx.x & 63;
    int hd = lane >> 4, k = lane & 15;
    int d = cnt2[u];
    int base = u * CAP;
    float a0 = 0.f, a1 = 0.f, a2 = 0.f, a3 = 0.f;
    int p = 0;
    for (; p + 4 <= d; p += 4) {
        int q = base + p;
        int c0 = cols[q], c1_ = cols[q + 1], c2 = cols[q + 2], c3 = cols[q + 3];
        float f0 = val4[4 * q + hd];
        float f1 = val4[4 * (q + 1) + hd];
        float f2 = val4[4 * (q + 2) + hd];
        float f3 = val4[4 * (q + 3) + hd];
        a0 += f0 * __bfloat162float(x[c0 + lane]);
        a1 += f1 * __bfloat162float(x[c1_ + lane]);
        a2 += f2 * __bfloat162float(x[c2 + lane]);
        a3 += f3 * __bfloat162float(x[c3 + lane]);
    }
    for (; p < d; p++) {
        int q = base + p;
        a0 += val4[4 * q + hd] * __bfloat162float(x[cols[q] + lane]);
    }
    float acc = (a0 + a1) + (a2 + a3);
    float r = s_k * acc + c_k * h_perm[(u << 6) + lane];
    out[hd * (Nn * DK) + u * DK + k] = r;   // native layout
}

// ---------------------------------------------------------------------------
extern "C" void kernel_launch(void* const* d_in, const int* in_sizes, int n_in,
                              void* d_out, int out_size, void* d_ws, size_t ws_size,
                              hipStream_t stream) {
    const float* h = (const float*)d_in[0];
    const float* e = (const float*)d_in[1];
    const int* src = (const int*)d_in[2];
    const int* dst = (const int*)d_in[3];
    float* out = (float*)d_out;

    // Workspace carve-up (~30 MB)
    char* ws = (char*)d_ws;
    size_t off = 0;
    auto alloc = [&](size_t bytes) -> void* {
        void* p = ws + off;
        off = (off + bytes + 255) & ~(size_t)255;
        return p;
    };
    int*            cnt    = (int*)            alloc((size_t)Nn * 4);
    int*            cnt2   = (int*)            alloc((size_t)Nn * 4);
    unsigned*       bucket = (unsigned*)       alloc((size_t)Nn * CAP * 4);      // 4 MB
    int*            cols   = (int*)            alloc((size_t)Nn * CAP * 4);      // 4 MB
    float*          val4   = (float*)          alloc((size_t)Nn * CAP * 4 * 4);  // 16 MB
    float*          h_perm = (float*)          alloc((size_t)XLEN * 4);          // 2 MB
    float4*         e4     = (float4*)         alloc((size_t)Ee * 16);           // 2 MB
    __hip_bfloat16* bufA   = (__hip_bfloat16*) alloc((size_t)XLEN * 2);          // 1 MB
    __hip_bfloat16* bufB   = (__hip_bfloat16*) alloc((size_t)XLEN * 2);          // 1 MB

    const int tpb = 256;

    permute_kernel<<<XLEN / tpb, tpb, 0, stream>>>(h, h_perm, e, e4, cnt);
    scatter_kernel<<<(2 * Ee) / tpb, tpb, 0, stream>>>(src, dst, cnt, bucket);

    // Horner: r1 = (1/720) a h + (1/120) h; r_{k+1} = a r_k + c_k h; out = r6
    const float s_k[6] = {1.f / 720.f, 1.f, 1.f, 1.f, 1.f, 1.f};
    const float c_k[6] = {1.f / 120.f, 1.f / 24.f, 1.f / 6.f, 0.5f, 1.f, 1.f};

    dedup_s1_kernel<<<Nn / 4, tpb, 0, stream>>>(cnt, bucket, e4, h_perm, cnt2,
                                                cols, val4, bufA, s_k[0], c_k[0]);
    spmv_kernel<<<Nn / 4, tpb, 0, stream>>>(cnt2, cols, val4, bufA, h_perm, bufB, s_k[1], c_k[1]);
    spmv_kernel<<<Nn / 4, tpb, 0, stream>>>(cnt2, cols, val4, bufB, h_perm, bufA, s_k[2], c_k[2]);
    spmv_kernel<<<Nn / 4, tpb, 0, stream>>>(cnt2, cols, val4, bufA, h_perm, bufB, s_k[3], c_k[3]);
    spmv_kernel<<<Nn / 4, tpb, 0, stream>>>(cnt2, cols, val4, bufB, h_perm, bufA, s_k[4], c_k[4]);
    spmv_last_kernel<<<Nn / 4, tpb, 0, stream>>>(cnt2, cols, val4, bufA, h_perm, out, s_k[5], c_k[5]);
}